// Round 2
// baseline (5983.019 us; speedup 1.0000x reference)
//
#include <hip/hip_runtime.h>
#include <cstdint>

// CRF2 forward: B=64, S=1024, K=64.
// Design: 256 WGs x 512 thr. WG (b, c): batch b = wg>>2, j-chunk c = wg&3 (16 j's).
// T chunk [kp 0..31][i 0..63][jc 0..15] as f16x2 (k-pairs) resident in LDS (128KB).
// State At[i][k] = A[k][i] as f16 hi/lo pairs in LDS; per-step 4-WG exchange of
// A' chunks through agent-scope (cache-bypassing) stores/loads + flag counter.

#define THREADS 512
#define ATP_PITCH 34   // uint2 per row (pad: broadcast reads conflict-free, 16B align)
#define TL_BYTES 131072
#define ATP_BYTES (64 * ATP_PITCH * 8)
#define YP_BYTES (8 * 16 * 4)
#define LDS_BYTES (TL_BYTES + ATP_BYTES + YP_BYTES)

typedef _Float16 f16;
typedef _Float16 f16x2 __attribute__((ext_vector_type(2)));
typedef unsigned int u32;
typedef unsigned short u16;

static __device__ inline float fdot2_(u32 a, u32 b, float c) {
  f16x2 av = __builtin_bit_cast(f16x2, a);
  f16x2 bv = __builtin_bit_cast(f16x2, b);
#if __has_builtin(__builtin_amdgcn_fdot2)
  return __builtin_amdgcn_fdot2(av, bv, c, false);
#else
  c = __builtin_fmaf((float)av[0], (float)bv[0], c);
  return __builtin_fmaf((float)av[1], (float)bv[1], c);
#endif
}

static __device__ inline u32 pack_hilo(float v) {
  f16 h = (f16)v;
  f16 l = (f16)(v - (float)h);
  return (u32)__builtin_bit_cast(u16, h) | ((u32)__builtin_bit_cast(u16, l) << 16);
}

static __device__ inline void st_agent(u32* p, u32 v) {
  __hip_atomic_store(p, v, __ATOMIC_RELAXED, __HIP_MEMORY_SCOPE_AGENT);
}
static __device__ inline u32 ld_agent(const u32* p) {
  return __hip_atomic_load(p, __ATOMIC_RELAXED, __HIP_MEMORY_SCOPE_AGENT);
}

// ---- prep: T fp32 -> f16x2 packed chunks [c][kp][i][jc]; zero flags ----
__global__ void prep_kernel(const float* __restrict__ T, u32* __restrict__ wsT,
                            int* __restrict__ flags) {
  int idx = blockIdx.x * 256 + threadIdx.x;   // 0..131071
  int jc = idx & 15;
  int i  = (idx >> 4) & 63;
  int kp = (idx >> 10) & 31;
  int c  = idx >> 15;
  int j  = c * 16 + jc;
  int k0 = kp * 2;
  float f0 = T[(k0)     * 4096 + i * 64 + j];
  float f1 = T[(k0 + 1) * 4096 + i * 64 + j];
  f16 h0 = (f16)f0, h1 = (f16)f1;
  wsT[idx] = (u32)__builtin_bit_cast(u16, h0) | ((u32)__builtin_bit_cast(u16, h1) << 16);
  if (idx < 128) flags[idx] = 0;
}

// ---- main persistent kernel ----
__global__ __launch_bounds__(THREADS, 1)
void crf_kernel(const float* __restrict__ X, const u32* __restrict__ wsT,
                u32* __restrict__ wsA, int* __restrict__ flags,
                float* __restrict__ Y) {
  extern __shared__ char smem[];
  u32*   Tl  = (u32*)smem;                       // [32][64][16] f16x2
  uint2* Atp = (uint2*)(smem + TL_BYTES);        // [64][ATP_PITCH] {hi-pair, lo-pair}
  float* yp  = (float*)(smem + TL_BYTES + ATP_BYTES);  // [8][16]

  const int wg   = blockIdx.x;
  const int b    = wg >> 2;
  const int c    = wg & 3;
  const int tid  = threadIdx.x;
  const int wave = tid >> 6;
  const int lane = tid & 63;
  const int i4   = lane >> 4;
  const int jc   = lane & 15;
  const int jglob = c * 16 + jc;

  // stage T chunk -> LDS (contiguous, coalesced)
  {
    const uint4* src = (const uint4*)(wsT + c * 32768);
    uint4* dst = (uint4*)Tl;
#pragma unroll
    for (int q = 0; q < 16; ++q) dst[q * 512 + tid] = src[q * 512 + tid];
  }
  // init state: At0[i][k] = x0[i]/64 (constant across k)
#pragma unroll
  for (int s = 0; s < 4; ++s) {
    int e = s * 512 + tid;          // 0..2047
    int i = e >> 5, kp = e & 31;
    (void)kp;
    float v = X[b * 65536 + i] * (1.0f / 64.0f);
    f16 h = (f16)v;
    f16 l = (f16)(v - (float)h);
    u32 hb = (u32)__builtin_bit_cast(u16, h);
    u32 lb = (u32)__builtin_bit_cast(u16, l);
    Atp[i * ATP_PITCH + (e & 31)] = make_uint2(hb | (hb << 16), lb | (lb << 16));
  }
  // y[:,0,:] = x0
  if (tid < 16) Y[b * 65536 + c * 16 + tid] = X[b * 65536 + c * 16 + tid];
  __syncthreads();

  const int ia  = wave * 4 + i4;        // first i-group
  const int ib2 = (wave + 8) * 4 + i4;  // second i-group
  int* cnt = flags + b * 2;

  float xcur = X[(b * 1024 + 1) * 64 + jglob];

  for (int t = 1; t < 1024; ++t) {
    const int p = t & 1;
    const int gen = (t + p) >> 1;

    // ---- compute M rows for our two i-groups ----
    float m0h = 0.f, m0l = 0.f, m1h = 0.f, m1l = 0.f;
    const u32* TlA = Tl + ia * 16 + jc;
    const u32* TlB = Tl + ib2 * 16 + jc;
    const uint2* ApA = Atp + ia * ATP_PITCH;
    const uint2* ApB = Atp + ib2 * ATP_PITCH;
#pragma unroll 8
    for (int kp = 0; kp < 32; ++kp) {
      u32 tA = TlA[kp * 1024];
      uint2 aA = ApA[kp];
      m0h = fdot2_(aA.x, tA, m0h);
      m0l = fdot2_(aA.y, tA, m0l);
      u32 tB = TlB[kp * 1024];
      uint2 aB = ApB[kp];
      m1h = fdot2_(aB.x, tB, m1h);
      m1l = fdot2_(aB.y, tB, m1l);
    }
    float anew0 = xcur * (m0h + m0l);
    float anew1 = xcur * (m1h + m1l);

    // ---- y partial: sum over this wave's 8 i's ----
    float ysum = anew0 + anew1;
    ysum += __shfl_xor(ysum, 16);
    ysum += __shfl_xor(ysum, 32);
    if (i4 == 0) yp[wave * 16 + jc] = ysum;

    // ---- publish our A' chunk (device-coherent stores) ----
    const int slot = ((b * 2 + p) * 4 + c) * 1024;
    st_agent(&wsA[slot + ia * 16 + jc], pack_hilo(anew0));
    st_agent(&wsA[slot + ib2 * 16 + jc], pack_hilo(anew1));
    asm volatile("s_waitcnt vmcnt(0)" ::: "memory");
    __syncthreads();   // all stores drained; yp complete
    if (tid == 0)
      __hip_atomic_fetch_add(&cnt[p], 1, __ATOMIC_RELAXED, __HIP_MEMORY_SCOPE_AGENT);

    // y reduce + store (overlaps peers' arrival)
    if (tid < 16) {
      float y = 0.f;
#pragma unroll
      for (int w = 0; w < 8; ++w) y += yp[w * 16 + tid];
      Y[(b * 1024 + t) * 64 + c * 16 + tid] = y;
    }
    if (tid == 0) {
      const int target = 4 * gen;
      int guard = 0;
      while (__hip_atomic_load(&cnt[p], __ATOMIC_RELAXED, __HIP_MEMORY_SCOPE_AGENT) < target) {
        __builtin_amdgcn_s_sleep(2);
        if (++guard > (1 << 22)) break;  // safety against non-resident deadlock
      }
    }
    __syncthreads();

    // ---- rebuild At for next step from all 4 chunks; prefetch x ----
    float xn = 0.f;
    if (t < 1023) xn = X[(b * 1024 + t + 1) * 64 + jglob];
    {
      const int base = (b * 2 + p) * 4 * 1024;
#pragma unroll
      for (int s = 0; s < 4; ++s) {
        int e = s * 512 + tid;          // 0..2047
        int alow = e & 15;
        int kp = (e >> 4) & 31;
        int chi = e >> 9;               // source chunk
        int a = chi * 16 + alow;        // At row
        u32 u0 = ld_agent(&wsA[base + chi * 1024 + (2 * kp) * 16 + alow]);
        u32 u1 = ld_agent(&wsA[base + chi * 1024 + (2 * kp + 1) * 16 + alow]);
        Atp[a * ATP_PITCH + kp] =
            make_uint2((u0 & 0xFFFFu) | (u1 << 16), (u0 >> 16) | (u1 & 0xFFFF0000u));
      }
    }
    __syncthreads();
    xcur = xn;
  }
}

extern "C" void kernel_launch(void* const* d_in, const int* in_sizes, int n_in,
                              void* d_out, int out_size, void* d_ws, size_t ws_size,
                              hipStream_t stream) {
  const float* X = (const float*)d_in[0];
  const float* T = (const float*)d_in[1];
  float* Y = (float*)d_out;
  u32* wsT = (u32*)d_ws;                                   // 512 KB
  u32* wsA = (u32*)((char*)d_ws + (512 << 10));            // 2 MB
  int* flags = (int*)((char*)d_ws + (512 << 10) + (2 << 20));  // 512 B

  hipFuncSetAttribute((const void*)crf_kernel,
                      hipFuncAttributeMaxDynamicSharedMemorySize, LDS_BYTES);

  prep_kernel<<<512, 256, 0, stream>>>(T, wsT, flags);
  crf_kernel<<<256, THREADS, LDS_BYTES, stream>>>(X, wsT, wsA, flags, Y);
}

// Round 3
// 3503.606 us; speedup vs baseline: 1.7077x; 1.7077x over previous
//
#include <hip/hip_runtime.h>
#include <cstdint>

// CRF2 forward: B=64, S=1024, K=64.
// 256 WGs x 512 thr. WG (b,c): batch b = wg>>2, j-chunk c = wg&3 (16 j's).
// T chunk [kp][i][jc] f16x2 resident in LDS (128KB). State At[i][kp] hi/lo f16
// pairs in LDS. Per-step exchange: producers store tagged words (parity bit of
// generation embedded in lo-f16 bit0) to LLC via agent-scope stores; consumers
// poll payload parity directly. No counters, no fences, 2 barriers/step.

#define THREADS 512
#define ATP_PITCH 34   // uint2 per row
#define TL_BYTES 131072
#define ATP_BYTES (64 * ATP_PITCH * 8)
#define YP_BYTES (8 * 16 * 4)
#define LDS_BYTES (TL_BYTES + ATP_BYTES + YP_BYTES)

typedef _Float16 f16;
typedef _Float16 f16x2 __attribute__((ext_vector_type(2)));
typedef unsigned int u32;
typedef unsigned short u16;

static __device__ inline float fdot2_(u32 a, u32 b, float c) {
  f16x2 av = __builtin_bit_cast(f16x2, a);
  f16x2 bv = __builtin_bit_cast(f16x2, b);
#if __has_builtin(__builtin_amdgcn_fdot2)
  return __builtin_amdgcn_fdot2(av, bv, c, false);
#else
  c = __builtin_fmaf((float)av[0], (float)bv[0], c);
  return __builtin_fmaf((float)av[1], (float)bv[1], c);
#endif
}

// publish word: hi f16 | (lo f16 with bit0 = parity) << 16
static __device__ inline u32 pack_tag(float v, u32 q) {
  f16 h = (f16)v;
  f16 l = (f16)(v - (float)h);
  u32 hb = (u32)__builtin_bit_cast(u16, h);
  u32 lb = (u32)__builtin_bit_cast(u16, l);
  lb = (lb & 0xFFFEu) | q;
  return hb | (lb << 16);
}

// own-direct At entry for rows (even k = v0, odd k = v1), lo bit0 cleared
static __device__ inline uint2 pack_pair(float v0, float v1) {
  f16 h0 = (f16)v0; f16 l0 = (f16)(v0 - (float)h0);
  f16 h1 = (f16)v1; f16 l1 = (f16)(v1 - (float)h1);
  u32 hb0 = (u32)__builtin_bit_cast(u16, h0);
  u32 lb0 = (u32)__builtin_bit_cast(u16, l0) & 0xFFFEu;
  u32 hb1 = (u32)__builtin_bit_cast(u16, h1);
  u32 lb1 = (u32)__builtin_bit_cast(u16, l1) & 0xFFFEu;
  return make_uint2(hb0 | (hb1 << 16), lb0 | (lb1 << 16));
}

static __device__ inline void st_agent(u32* p, u32 v) {
  __hip_atomic_store(p, v, __ATOMIC_RELAXED, __HIP_MEMORY_SCOPE_AGENT);
}
static __device__ inline u32 ld_agent(const u32* p) {
  return __hip_atomic_load(p, __ATOMIC_RELAXED, __HIP_MEMORY_SCOPE_AGENT);
}

// ---- prep: T fp32 -> f16x2 packed chunks [c][kp][i][jc]; init wsA parity ----
__global__ void prep_kernel(const float* __restrict__ T, u32* __restrict__ wsT,
                            u32* __restrict__ wsA) {
  int idx = blockIdx.x * 256 + threadIdx.x;   // 0..131071
  int jc = idx & 15;
  int i  = (idx >> 4) & 63;
  int kp = (idx >> 10) & 31;
  int c  = idx >> 15;
  int j  = c * 16 + jc;
  int k0 = kp * 2;
  float f0 = T[(k0)     * 4096 + i * 64 + j];
  float f1 = T[(k0 + 1) * 4096 + i * 64 + j];
  f16 h0 = (f16)f0, h1 = (f16)f1;
  wsT[idx] = (u32)__builtin_bit_cast(u16, h0) | ((u32)__builtin_bit_cast(u16, h1) << 16);
  // wsA: [b][p][chunk][k][jc] words; 2*64*4096 = 524288 words, 4 per thread.
  // slot p first used at t=p? slot1 first used t=1 (q=0) -> init parity 1;
  // slot0 first used t=2 (q=1) -> init parity 0.
#pragma unroll
  for (int r = 0; r < 4; ++r) {
    int w = idx * 4 + r;
    int p = (w >> 12) & 1;
    wsA[w] = p ? 0x00010000u : 0u;
  }
}

// ---- main persistent kernel ----
__global__ __launch_bounds__(THREADS, 1)
void crf_kernel(const float* __restrict__ X, const u32* __restrict__ wsT,
                u32* __restrict__ wsA, float* __restrict__ Y) {
  extern __shared__ char smem[];
  u32*   Tl  = (u32*)smem;                       // [32][64][16] f16x2
  uint2* Atp = (uint2*)(smem + TL_BYTES);        // [64][ATP_PITCH] {hi-pair, lo-pair}
  float* yp  = (float*)(smem + TL_BYTES + ATP_BYTES);  // [8][16]

  const int wg   = blockIdx.x;
  const int b    = wg >> 2;
  const int c    = wg & 3;
  const int tid  = threadIdx.x;
  const int wave = tid >> 6;
  const int lane = tid & 63;
  const int i4   = lane >> 4;
  const int jc   = lane & 15;
  const int jglob = c * 16 + jc;

  // stage T chunk -> LDS
  {
    const uint4* src = (const uint4*)(wsT + c * 32768);
    uint4* dst = (uint4*)Tl;
#pragma unroll
    for (int qq = 0; qq < 16; ++qq) dst[qq * 512 + tid] = src[qq * 512 + tid];
  }
  // init state: At0[i][k] = x0[i]/64 (constant across k)
#pragma unroll
  for (int s = 0; s < 4; ++s) {
    int e = s * 512 + tid;          // 0..2047
    int i = e >> 5;
    float v = X[b * 65536 + i] * (1.0f / 64.0f);
    f16 h = (f16)v;
    f16 l = (f16)(v - (float)h);
    u32 hb = (u32)__builtin_bit_cast(u16, h);
    u32 lb = (u32)__builtin_bit_cast(u16, l) & 0xFFFEu;
    Atp[i * ATP_PITCH + (e & 31)] = make_uint2(hb | (hb << 16), lb | (lb << 16));
  }
  if (tid < 16) Y[b * 65536 + c * 16 + tid] = X[b * 65536 + c * 16 + tid];
  __syncthreads();

  const int ia  = wave * 4 + i4;        // 0..31
  const int ib2 = ia + 32;              // 32..63
  // remote chunks and fixed gather coords
  const int kp_g = tid >> 4;            // 0..31
  const int alow = tid & 15;

  float xcur = X[(b * 1024 + 1) * 64 + jglob];

  for (int t = 1; t < 1024; ++t) {
    const int p = t & 1;
    const u32 q = (u32)((t >> 1) & 1);

    // ---- phase A: compute (reads Tl, Atp) ----
    float m0h = 0.f, m0l = 0.f, m1h = 0.f, m1l = 0.f;
    const u32* TlA = Tl + ia * 16 + jc;
    const u32* TlB = Tl + ib2 * 16 + jc;
    const uint2* ApA = Atp + ia * ATP_PITCH;
    const uint2* ApB = Atp + ib2 * ATP_PITCH;
#pragma unroll 8
    for (int kp = 0; kp < 32; ++kp) {
      u32 tA = TlA[kp * 1024];
      uint2 aA = ApA[kp];
      m0h = fdot2_(aA.x, tA, m0h);
      m0l = fdot2_(aA.y, tA, m0l);
      u32 tB = TlB[kp * 1024];
      uint2 aB = ApB[kp];
      m1h = fdot2_(aB.x, tB, m1h);
      m1l = fdot2_(aB.y, tB, m1l);
    }
    float anew0 = xcur * (m0h + m0l);
    float anew1 = xcur * (m1h + m1l);

    // y partial across this wave's 8 rows
    float ysum = anew0 + anew1;
    ysum += __shfl_xor(ysum, 16);
    ysum += __shfl_xor(ysum, 32);
    if (i4 == 0) yp[wave * 16 + jc] = ysum;

    // publish tagged words (register-only; before barrier, no drain needed)
    const int sb = (b * 2 + p) * 4096;
    if (t < 1023) {
      st_agent(&wsA[sb + c * 1024 + ia * 16 + jc], pack_tag(anew0, q));
      st_agent(&wsA[sb + c * 1024 + ib2 * 16 + jc], pack_tag(anew1, q));
    }
    // partner values for own-direct (all lanes execute shfl)
    float pb0 = __shfl_xor(anew0, 16);
    float pb1 = __shfl_xor(anew1, 16);

    __syncthreads();   // At reads done; yp visible

    // ---- phase B ----
    if (tid < 16) {
      float y = 0.f;
#pragma unroll
      for (int w = 0; w < 8; ++w) y += yp[w * 16 + tid];
      Y[(b * 1024 + t) * 64 + c * 16 + tid] = y;
    }
    float xn = 0.f;
    if (t < 1023) {
      xn = X[(b * 1024 + t + 1) * 64 + jglob];

      // own chunk: registers -> LDS directly (even-i4 lanes write k-pairs)
      if (!(i4 & 1)) {
        Atp[jglob * ATP_PITCH + (ia >> 1)]  = pack_pair(anew0, pb0);
        Atp[jglob * ATP_PITCH + (ib2 >> 1)] = pack_pair(anew1, pb1);
      }

      // gather 3 remote chunks: one (kp,alow) entry per chunk per thread
      int a0[3], a1[3];
#pragma unroll
      for (int s = 0; s < 3; ++s) {
        int chi = (c + 1 + s) & 3;
        int base = sb + chi * 1024 + (2 * kp_g) * 16 + alow;
        a0[s] = base; a1[s] = base + 16;
      }
      u32 w0[3], w1[3];
      u32 pend = 7; int guard = 0;
      const u32 qmask = q << 16;
      while (pend) {
#pragma unroll
        for (int s = 0; s < 3; ++s) {
          if (pend & (1u << s)) {
            u32 x0 = ld_agent(&wsA[a0[s]]);
            u32 x1 = ld_agent(&wsA[a1[s]]);
            if ((((x0 ^ qmask) | (x1 ^ qmask)) & 0x00010000u) == 0) {
              w0[s] = x0; w1[s] = x1; pend &= ~(1u << s);
            }
          }
        }
        if (pend && ++guard > (1 << 20)) break;  // safety valve
      }
#pragma unroll
      for (int s = 0; s < 3; ++s) {
        int chi = (c + 1 + s) & 3;
        u32 hip = (w0[s] & 0xFFFFu) | (w1[s] << 16);
        u32 lop = ((w0[s] >> 16) | (w1[s] & 0xFFFF0000u)) & 0xFFFEFFFEu;
        Atp[(chi * 16 + alow) * ATP_PITCH + kp_g] = make_uint2(hip, lop);
      }
    }
    __syncthreads();
    xcur = xn;
  }
}

extern "C" void kernel_launch(void* const* d_in, const int* in_sizes, int n_in,
                              void* d_out, int out_size, void* d_ws, size_t ws_size,
                              hipStream_t stream) {
  const float* X = (const float*)d_in[0];
  const float* T = (const float*)d_in[1];
  float* Y = (float*)d_out;
  u32* wsT = (u32*)d_ws;                                   // 512 KB
  u32* wsA = (u32*)((char*)d_ws + (512 << 10));            // 2 MB

  hipFuncSetAttribute((const void*)crf_kernel,
                      hipFuncAttributeMaxDynamicSharedMemorySize, LDS_BYTES);

  prep_kernel<<<512, 256, 0, stream>>>(T, wsT, wsA);
  crf_kernel<<<256, THREADS, LDS_BYTES, stream>>>(X, wsT, wsA, Y);
}

// Round 4
// 2728.116 us; speedup vs baseline: 2.1931x; 1.2843x over previous
//
#include <hip/hip_runtime.h>
#include <cstdint>

// CRF2 forward: B=64, S=1024, K=64.
// 256 WGs x 512 thr. WG (b,c): batch b = wg>>2, j-chunk c = wg&3 (16 j's).
// T slice held in REGISTERS per thread (64 u32 = 2 i-rows x 32 k-pairs x own jc),
// staged once via LDS. State At[i][kp] hi/lo f16 pairs in LDS (broadcast reads).
// Per-step exchange: tagged words (generation parity in lo-f16 bit0) through
// LLC via agent-scope stores; consumers poll payload parity. 2 barriers/step.

#define THREADS 512
#define ATP_PITCH 34   // uint2 per row
#define TL_BYTES 131072
#define ATP_BYTES (64 * ATP_PITCH * 8)
#define YP_BYTES (8 * 16 * 4)
#define LDS_BYTES (TL_BYTES + ATP_BYTES + YP_BYTES)

typedef _Float16 f16;
typedef _Float16 f16x2 __attribute__((ext_vector_type(2)));
typedef unsigned int u32;
typedef unsigned short u16;

static __device__ inline float fdot2_(u32 a, u32 b, float c) {
  f16x2 av = __builtin_bit_cast(f16x2, a);
  f16x2 bv = __builtin_bit_cast(f16x2, b);
#if __has_builtin(__builtin_amdgcn_fdot2)
  return __builtin_amdgcn_fdot2(av, bv, c, false);
#else
  c = __builtin_fmaf((float)av[0], (float)bv[0], c);
  return __builtin_fmaf((float)av[1], (float)bv[1], c);
#endif
}

// publish word: hi f16 | (lo f16 with bit0 = parity) << 16
static __device__ inline u32 pack_tag(float v, u32 q) {
  f16 h = (f16)v;
  f16 l = (f16)(v - (float)h);
  u32 hb = (u32)__builtin_bit_cast(u16, h);
  u32 lb = (u32)__builtin_bit_cast(u16, l);
  lb = (lb & 0xFFFEu) | q;
  return hb | (lb << 16);
}

// own-direct At entry for rows (even k = v0, odd k = v1), lo bit0 cleared
static __device__ inline uint2 pack_pair(float v0, float v1) {
  f16 h0 = (f16)v0; f16 l0 = (f16)(v0 - (float)h0);
  f16 h1 = (f16)v1; f16 l1 = (f16)(v1 - (float)h1);
  u32 hb0 = (u32)__builtin_bit_cast(u16, h0);
  u32 lb0 = (u32)__builtin_bit_cast(u16, l0) & 0xFFFEu;
  u32 hb1 = (u32)__builtin_bit_cast(u16, h1);
  u32 lb1 = (u32)__builtin_bit_cast(u16, l1) & 0xFFFEu;
  return make_uint2(hb0 | (hb1 << 16), lb0 | (lb1 << 16));
}

static __device__ inline void st_agent(u32* p, u32 v) {
  __hip_atomic_store(p, v, __ATOMIC_RELAXED, __HIP_MEMORY_SCOPE_AGENT);
}
static __device__ inline u32 ld_agent(const u32* p) {
  return __hip_atomic_load(p, __ATOMIC_RELAXED, __HIP_MEMORY_SCOPE_AGENT);
}

// ---- prep: T fp32 -> f16x2 packed chunks [c][kp][i][jc]; init wsA parity ----
__global__ void prep_kernel(const float* __restrict__ T, u32* __restrict__ wsT,
                            u32* __restrict__ wsA) {
  int idx = blockIdx.x * 256 + threadIdx.x;   // 0..131071
  int jc = idx & 15;
  int i  = (idx >> 4) & 63;
  int kp = (idx >> 10) & 31;
  int c  = idx >> 15;
  int j  = c * 16 + jc;
  int k0 = kp * 2;
  float f0 = T[(k0)     * 4096 + i * 64 + j];
  float f1 = T[(k0 + 1) * 4096 + i * 64 + j];
  f16 h0 = (f16)f0, h1 = (f16)f1;
  wsT[idx] = (u32)__builtin_bit_cast(u16, h0) | ((u32)__builtin_bit_cast(u16, h1) << 16);
  // wsA parity init: slot1 first used t=1 (q=0) -> parity 1; slot0 t=2 (q=1) -> 0.
#pragma unroll
  for (int r = 0; r < 4; ++r) {
    int w = idx * 4 + r;
    int p = (w >> 12) & 1;
    wsA[w] = p ? 0x00010000u : 0u;
  }
}

// ---- main persistent kernel ----
__global__ __launch_bounds__(THREADS, 1)
void crf_kernel(const float* __restrict__ X, const u32* __restrict__ wsT,
                u32* __restrict__ wsA, float* __restrict__ Y) {
  extern __shared__ char smem[];
  u32*   Tl  = (u32*)smem;                       // [32][64][16] staging only
  uint2* Atp = (uint2*)(smem + TL_BYTES);        // [64][ATP_PITCH] {hi-pair, lo-pair}
  float* yp  = (float*)(smem + TL_BYTES + ATP_BYTES);  // [8][16]

  const int wg   = blockIdx.x;
  const int b    = wg >> 2;
  const int c    = wg & 3;
  const int tid  = threadIdx.x;
  const int wave = tid >> 6;
  const int lane = tid & 63;
  const int i4   = lane >> 4;
  const int jc   = lane & 15;
  const int jglob = c * 16 + jc;

  // stage T chunk -> LDS (coalesced), then pull per-thread slice into registers
  {
    const uint4* src = (const uint4*)(wsT + c * 32768);
    uint4* dst = (uint4*)Tl;
#pragma unroll
    for (int qq = 0; qq < 16; ++qq) dst[qq * 512 + tid] = src[qq * 512 + tid];
  }
  // init state: At0[i][k] = x0[i]/64 (constant across k)
#pragma unroll
  for (int s = 0; s < 4; ++s) {
    int e = s * 512 + tid;          // 0..2047
    int i = e >> 5;
    float v = X[b * 65536 + i] * (1.0f / 64.0f);
    f16 h = (f16)v;
    f16 l = (f16)(v - (float)h);
    u32 hb = (u32)__builtin_bit_cast(u16, h);
    u32 lb = (u32)__builtin_bit_cast(u16, l) & 0xFFFEu;
    Atp[i * ATP_PITCH + (e & 31)] = make_uint2(hb | (hb << 16), lb | (lb << 16));
  }
  if (tid < 16) Y[b * 65536 + c * 16 + tid] = X[b * 65536 + c * 16 + tid];
  __syncthreads();

  const int ia  = wave * 4 + i4;        // 0..31
  const int ib2 = ia + 32;              // 32..63

  // T slice to registers: tA[kp] = T[kp][ia][jc], tB[kp] = T[kp][ib2][jc]
  u32 tA[32], tB[32];
#pragma unroll
  for (int kp = 0; kp < 32; ++kp) {
    tA[kp] = Tl[kp * 1024 + ia * 16 + jc];
    tB[kp] = Tl[kp * 1024 + ib2 * 16 + jc];
  }

  // remote gather fixed coords
  const int kp_g = tid >> 4;            // 0..31
  const int alow = tid & 15;

  float xcur = X[(b * 1024 + 1) * 64 + jglob];

  for (int t = 1; t < 1024; ++t) {
    const int p = t & 1;
    const u32 q = (u32)((t >> 1) & 1);

    // ---- phase A: compute (A from LDS broadcast, T from registers) ----
    float m0h = 0.f, m0l = 0.f, m1h = 0.f, m1l = 0.f;
    const uint2* ApA = Atp + ia * ATP_PITCH;
    const uint2* ApB = Atp + ib2 * ATP_PITCH;
#pragma unroll
    for (int kp = 0; kp < 32; ++kp) {
      uint2 aA = ApA[kp];
      m0h = fdot2_(aA.x, tA[kp], m0h);
      m0l = fdot2_(aA.y, tA[kp], m0l);
      uint2 aB = ApB[kp];
      m1h = fdot2_(aB.x, tB[kp], m1h);
      m1l = fdot2_(aB.y, tB[kp], m1l);
    }
    float anew0 = xcur * (m0h + m0l);
    float anew1 = xcur * (m1h + m1l);

    // y partial across this wave's 8 rows
    float ysum = anew0 + anew1;
    ysum += __shfl_xor(ysum, 16);
    ysum += __shfl_xor(ysum, 32);
    if (i4 == 0) yp[wave * 16 + jc] = ysum;

    // publish tagged words (fire-and-forget; no drain)
    const int sb = (b * 2 + p) * 4096;
    if (t < 1023) {
      st_agent(&wsA[sb + c * 1024 + ia * 16 + jc], pack_tag(anew0, q));
      st_agent(&wsA[sb + c * 1024 + ib2 * 16 + jc], pack_tag(anew1, q));
    }
    // partner values for own-direct (all lanes execute shfl)
    float pb0 = __shfl_xor(anew0, 16);
    float pb1 = __shfl_xor(anew1, 16);

    __syncthreads();   // At reads done; yp visible

    // ---- phase B ----
    if (tid < 16) {
      float y = 0.f;
#pragma unroll
      for (int w = 0; w < 8; ++w) y += yp[w * 16 + tid];
      Y[(b * 1024 + t) * 64 + c * 16 + tid] = y;
    }
    float xn = 0.f;
    if (t < 1023) {
      xn = X[(b * 1024 + t + 1) * 64 + jglob];

      // own chunk: registers -> LDS directly (even-i4 lanes write k-pairs)
      if (!(i4 & 1)) {
        Atp[jglob * ATP_PITCH + (ia >> 1)]  = pack_pair(anew0, pb0);
        Atp[jglob * ATP_PITCH + (ib2 >> 1)] = pack_pair(anew1, pb1);
      }

      // gather 3 remote chunks: one (kp,alow) entry per chunk per thread
      int a0[3], a1[3];
#pragma unroll
      for (int s = 0; s < 3; ++s) {
        int chi = (c + 1 + s) & 3;
        int base = sb + chi * 1024 + (2 * kp_g) * 16 + alow;
        a0[s] = base; a1[s] = base + 16;
      }
      u32 w0[3], w1[3];
      u32 pend = 7; int guard = 0;
      const u32 qmask = q << 16;
      while (pend) {
#pragma unroll
        for (int s = 0; s < 3; ++s) {
          if (pend & (1u << s)) {
            u32 x0 = ld_agent(&wsA[a0[s]]);
            u32 x1 = ld_agent(&wsA[a1[s]]);
            if ((((x0 ^ qmask) | (x1 ^ qmask)) & 0x00010000u) == 0) {
              w0[s] = x0; w1[s] = x1; pend &= ~(1u << s);
            }
          }
        }
        if (pend && ++guard > (1 << 20)) break;  // safety valve
      }
#pragma unroll
      for (int s = 0; s < 3; ++s) {
        int chi = (c + 1 + s) & 3;
        u32 hip = (w0[s] & 0xFFFFu) | (w1[s] << 16);
        u32 lop = ((w0[s] >> 16) | (w1[s] & 0xFFFF0000u)) & 0xFFFEFFFEu;
        Atp[(chi * 16 + alow) * ATP_PITCH + kp_g] = make_uint2(hip, lop);
      }
    }
    __syncthreads();
    xcur = xn;
  }
}

extern "C" void kernel_launch(void* const* d_in, const int* in_sizes, int n_in,
                              void* d_out, int out_size, void* d_ws, size_t ws_size,
                              hipStream_t stream) {
  const float* X = (const float*)d_in[0];
  const float* T = (const float*)d_in[1];
  float* Y = (float*)d_out;
  u32* wsT = (u32*)d_ws;                                   // 512 KB
  u32* wsA = (u32*)((char*)d_ws + (512 << 10));            // 2 MB

  hipFuncSetAttribute((const void*)crf_kernel,
                      hipFuncAttributeMaxDynamicSharedMemorySize, LDS_BYTES);

  prep_kernel<<<512, 256, 0, stream>>>(T, wsT, wsA);
  crf_kernel<<<256, THREADS, LDS_BYTES, stream>>>(X, wsT, wsA, Y);
}